// Round 5
// baseline (227.224 us; speedup 1.0000x reference)
//
#include <hip/hip_runtime.h>

#define NSTEPS 64

typedef __attribute__((ext_vector_type(16))) float float16_;   // 32x32 MFMA C/D
typedef __attribute__((ext_vector_type(2))) __fp16 half2_;     // packed f16
typedef __attribute__((ext_vector_type(8))) __fp16 half8_;     // f16 MFMA A/B operand

__device__ __forceinline__ half2_ relu_pk_f16(float a, float b) {
    half2_ h = __builtin_amdgcn_cvt_pkrtz(a, b);               // v_cvt_pkrtz_f16_f32
    return __builtin_elementwise_max(h, (half2_)(__fp16)0);    // v_pk_max_f16
}

// R13 layout (HW-verified; 32x32x16 f16 MFMA):
//   A[m][k]: m=lane&31, k=(lane>>5)*8+j
//   B[k][n]: n=lane&31, k=(lane>>5)*8+j
//   C/D[r][c]: c=lane&31, r=(reg&3)+8*(reg>>2)+4*(lane>>5)
//
// R19 (this round): latency-chain cuts. R2/R3/R4 all sat at ~170us kernel
// (~400 cyc/stage/wave) invariant to occupancy 19->31% => bound by the
// wave's own serial chain, not residency. Cuts:
//   a) A3 rows 4-6 duplicate rows 0-2 -> half=1 lanes' D3[0..2] hold k
//      directly; permlane/broadcast block deleted entirely.
//   b) L2/L3 MFMA pairs de-chained (independent C: bias/zero) and merged
//      by VALU adds -> removes serial C->D dependency between the pairs.
//   c) launch_bounds(256,4): at 52 arch VGPRs the unified demand fits the
//      128-reg cap; grid 1024 = 4 blocks/CU exactly -> balanced residency.
__global__ __launch_bounds__(256, 4)
void ode_rk4_mfma(const float* __restrict__ x,
                  const float* __restrict__ samples,
                  const float* __restrict__ w1, const float* __restrict__ b1,
                  const float* __restrict__ w2, const float* __restrict__ b2,
                  const float* __restrict__ w3, const float* __restrict__ b3,
                  const float* __restrict__ w_out, const float* __restrict__ b_out,
                  float* __restrict__ out, int B)
{
    const int lane  = threadIdx.x & 63;
    const int w     = threadIdx.x >> 6;
    const int col32 = lane & 31;              // this lane's sample row (mod 32)
    const int half  = lane >> 5;              // 0..1

    const int rowBase = (blockIdx.x * 4 + w) * 32;
    const int row = rowBase + col32;

    // pi permutation: swap hidden-unit 4-blocks 1<->2 and 5<->6
    auto pi = [](int m) -> int {
        int bb = (m >> 2) & 3;
        return m + ((bb == 1) ? 4 : (bb == 2) ? -4 : 0);
    };

    // ---- persistent MFMA operands ----
    // Layer1 A-frag: A1[m][k] = w1[k][pi(m)] for k=0..2, A1[m][3] = b1[pi(m)]
    // (B row 3 carries constant 1.0 -> bias folded, C is zero)
    union { half2_ h2[4]; half8_ h8; } A1;
    {
        int pm = pi(col32);
        if (half == 0) {
            A1.h2[0] = (half2_){(__fp16)w1[0 * 32 + pm], (__fp16)w1[1 * 32 + pm]};
            A1.h2[1] = (half2_){(__fp16)w1[2 * 32 + pm], (__fp16)b1[pm]};
        } else {
            A1.h2[0] = (half2_)(__fp16)0.0f;
            A1.h2[1] = (half2_)(__fp16)0.0f;
        }
        A1.h2[2] = (half2_)(__fp16)0.0f;
        A1.h2[3] = (half2_)(__fp16)0.0f;
    }

    // W2^T A-frags: A2[m=j2][k=i1] = w2[i1*32 + j2]
    union { half2_ h2[4]; half8_ h8; } W2T1, W2T2;
#pragma unroll
    for (int pp = 0; pp < 4; ++pp) {
        int i1 = half * 8 + 2 * pp;
        W2T1.h2[pp] = (half2_){(__fp16)w2[i1 * 32 + col32], (__fp16)w2[(i1 + 1) * 32 + col32]};
        W2T2.h2[pp] = (half2_){(__fp16)w2[(i1 + 16) * 32 + col32], (__fp16)w2[(i1 + 17) * 32 + col32]};
    }
    // layer2 bias C-frag: Cb[r] = b2[j2(r)]
    float16_ Cb;
#pragma unroll
    for (int r = 0; r < 16; ++r)
        Cb[r] = b2[(r & 3) + 8 * (r >> 2) + 4 * half];

    // Layer3 A-frags with ROW DUPLICATION: rows {0,1,2} AND {4,5,6} hold
    // w3 column (m&3); D3 regs 0..2 then hold k in BOTH lane-halves.
    // A3[m][k] = w3[nu(k)][m&3]; nu(16t+8h+j) = 16t + 4h + (j&3) + 8*(j>>2)
    union { half2_ h2[4]; half8_ h8; } A31, A32;
    {
        const bool live = (col32 < 8) && ((col32 & 3) < 3);
        const int  d    = col32 & 3;
#pragma unroll
        for (int pp = 0; pp < 4; ++pp) {
            int j0 = 2 * pp;
            int nu0 = 4 * half + (j0 & 3) + 8 * (j0 >> 2);
            if (live) {
                A31.h2[pp] = (half2_){(__fp16)w3[nu0 * 3 + d], (__fp16)w3[(nu0 + 1) * 3 + d]};
                A32.h2[pp] = (half2_){(__fp16)w3[(nu0 + 16) * 3 + d], (__fp16)w3[(nu0 + 17) * 3 + d]};
            } else {
                A31.h2[pp] = (half2_)(__fp16)0.0f;
                A32.h2[pp] = (half2_)(__fp16)0.0f;
            }
        }
    }

    // shared zero C-frag (layer1, layer2-second, layer3 both)
    float16_ Zc;
#pragma unroll
    for (int r = 0; r < 16; ++r) Zc[r] = 0.0f;

    // ---- scalars ----
    const float maxT = samples[7];
    const float dt   = maxT / 64.0f;
    const float dt2  = 0.5f * dt;
    const float dt6  = dt / 6.0f;

    int sidx[8];
    unsigned long long smask = 0ull;
#pragma unroll
    for (int j = 0; j < 8; ++j) {
        int id = (int)rintf(samples[j] / dt) - 1;   // jnp.round = RNE
        id = id < 0 ? 0 : (id > NSTEPS - 1 ? NSTEPS - 1 : id);
        id = __builtin_amdgcn_readfirstlane(id);    // wave-uniform -> SGPR
        sidx[j] = id;
        smask |= 1ull << id;
    }
    const float wo0 = w_out[0], wo1 = w_out[1], wo2 = w_out[2];
    const float bo  = b_out[0];
    const float b30 = b3[0], b31 = b3[1], b32 = b3[2];

    float y0 = x[(size_t)row * 3 + 0];
    float y1 = x[(size_t)row * 3 + 1];
    float y2 = x[(size_t)row * 3 + 2];

#pragma unroll 1
    for (int s = 0; s < NSTEPS; ++s) {
        float acc0 = 0.f, acc1 = 0.f, acc2 = 0.f;
        float a0 = y0, a1 = y1, a2 = y2;

#pragma unroll
        for (int st = 0; st < 4; ++st) {
            // ---- layer1 via MFMA; bias rides k=3 against the 1.0 in a2o ----
            half2_ a01 = __builtin_amdgcn_cvt_pkrtz(a0, a1);
            half2_ a2o = __builtin_amdgcn_cvt_pkrtz(a2, 1.0f);
            union { half2_ h2[4]; half8_ h8; } BL1;
            BL1.h2[0] = a01; BL1.h2[1] = a2o;
            BL1.h2[2] = a01; BL1.h2[3] = a2o;   // k>=8: A==0, don't-care

            float16_ D1 = __builtin_amdgcn_mfma_f32_32x32x16_f16(A1.h8, BL1.h8, Zc, 0, 0, 0);

            // ---- relu-pack -> layer2 B-frags (pi makes register order exact)
            union { half2_ h2[4]; half8_ h8; } B1, B2;
#pragma unroll
            for (int pp = 0; pp < 4; ++pp) {
                B1.h2[pp] = relu_pk_f16(D1[2 * pp], D1[2 * pp + 1]);
                B2.h2[pp] = relu_pk_f16(D1[8 + 2 * pp], D1[8 + 2 * pp + 1]);
            }

            // ---- layer2: two INDEPENDENT MFMAs (no C-chain), VALU merge ----
            float16_ D2a = __builtin_amdgcn_mfma_f32_32x32x16_f16(W2T1.h8, B1.h8, Cb, 0, 0, 0);
            float16_ D2b = __builtin_amdgcn_mfma_f32_32x32x16_f16(W2T2.h8, B2.h8, Zc, 0, 0, 0);

            // ---- merge + relu-pack -> layer3 B-frags ----
            union { half2_ h2[4]; half8_ h8; } H1, H2;
#pragma unroll
            for (int pp = 0; pp < 4; ++pp) {
                H1.h2[pp] = relu_pk_f16(D2a[2 * pp] + D2b[2 * pp],
                                        D2a[2 * pp + 1] + D2b[2 * pp + 1]);
                H2.h2[pp] = relu_pk_f16(D2a[8 + 2 * pp] + D2b[8 + 2 * pp],
                                        D2a[8 + 2 * pp + 1] + D2b[8 + 2 * pp + 1]);
            }

            // ---- layer3: two INDEPENDENT MFMAs; rows duplicated so every
            // lane's regs 0..2 hold its sample's k ----
            float16_ D3a = __builtin_amdgcn_mfma_f32_32x32x16_f16(A31.h8, H1.h8, Zc, 0, 0, 0);
            float16_ D3b = __builtin_amdgcn_mfma_f32_32x32x16_f16(A32.h8, H2.h8, Zc, 0, 0, 0);

            float k0 = D3a[0] + D3b[0] + b30;
            float k1 = D3a[1] + D3b[1] + b31;
            float k2 = D3a[2] + D3b[2] + b32;

            const float ca = (st == 1 || st == 2) ? 2.0f : 1.0f;
            acc0 = fmaf(ca, k0, acc0); acc1 = fmaf(ca, k1, acc1); acc2 = fmaf(ca, k2, acc2);
            const float ci = (st == 2) ? dt : dt2;
            a0 = fmaf(ci, k0, y0); a1 = fmaf(ci, k1, y1); a2 = fmaf(ci, k2, y2);
        }
        y0 = fmaf(dt6, acc0, y0); y1 = fmaf(dt6, acc1, y1); y2 = fmaf(dt6, acc2, y2);

        // wave-uniform SALU fast path: most steps store nothing
        if ((smask >> s) & 1ull) {
            if (half == 0) {
#pragma unroll
                for (int j = 0; j < 8; ++j) {
                    if (sidx[j] == s) {
                        out[(size_t)j * B + row] = fmaf(y2, wo2, fmaf(y1, wo1, fmaf(y0, wo0, bo)));
                    }
                }
            }
        }
    }
}

extern "C" void kernel_launch(void* const* d_in, const int* in_sizes, int n_in,
                              void* d_out, int out_size, void* d_ws, size_t ws_size,
                              hipStream_t stream) {
    const float* x       = (const float*)d_in[0];
    const float* samples = (const float*)d_in[1];
    const float* w1      = (const float*)d_in[2];
    const float* b1      = (const float*)d_in[3];
    const float* w2      = (const float*)d_in[4];
    const float* b2      = (const float*)d_in[5];
    const float* w3      = (const float*)d_in[6];
    const float* b3      = (const float*)d_in[7];
    const float* w_out   = (const float*)d_in[8];
    const float* b_out   = (const float*)d_in[9];
    float* out = (float*)d_out;

    const int B = in_sizes[0] / 3;           // 131072
    const int rowsPerBlock = 128;            // 4 waves x 32 rows (1 chain each)
    const int grid = (B + rowsPerBlock - 1) / rowsPerBlock;
    ode_rk4_mfma<<<grid, 256, 0, stream>>>(
        x, samples, w1, b1, w2, b2, w3, b3, w_out, b_out, out, B);
}

// Round 6
// 199.599 us; speedup vs baseline: 1.1384x; 1.1384x over previous
//
#include <hip/hip_runtime.h>

#define NSTEPS 64

typedef __attribute__((ext_vector_type(16))) float float16_;   // 32x32 MFMA C/D
typedef __attribute__((ext_vector_type(2))) __fp16 half2_;     // packed f16
typedef __attribute__((ext_vector_type(8))) __fp16 half8_;     // f16 MFMA A/B operand

__device__ __forceinline__ half2_ relu_pk_f16(float a, float b) {
    half2_ h = __builtin_amdgcn_cvt_pkrtz(a, b);               // v_cvt_pkrtz_f16_f32
    return __builtin_elementwise_max(h, (half2_)(__fp16)0);    // v_pk_max_f16
}

// R13 layout (HW-verified; 32x32x16 f16 MFMA):
//   A[m][k]: m=lane&31, k=(lane>>5)*8+j
//   B[k][n]: n=lane&31, k=(lane>>5)*8+j
//   C/D[r][c]: c=lane&31, r=(reg&3)+8*(reg>>2)+4*(lane>>5)
//
// R20 (this round): VALU-slot trim. R2-R5 showed wall tracks VALU issue
// count (wall 397 cyc/window vs 266 VALU + 160 MFMA), invariant to
// occupancy/latency tweaks. Cuts, keeping R4's fastest structure:
//  a) RK-fold into layer1: W1^T(y+ci*k) = W1^T y + ci*W1^T k. Two A1
//     variants (ci=dt2 / ci=dt); B = (y0,y1,y2,1 | k0,k1,k2,0). y-cvt
//     once per STEP; per stage only 2 k-cvts. Kills a-prep fmas + a regs.
//  b) A3 row-duplication (rows {0,1,2}+{4,5,6} carry w3; validated R5):
//     every lane's D3[0..2] = its k directly -> permlane block deleted.
//     L3 stays CHAINED (R5's de-chain+merge adds regressed).
//  c) L2 chained with Cb inner (R4 form).
__global__ __launch_bounds__(256, 4)
void ode_rk4_mfma(const float* __restrict__ x,
                  const float* __restrict__ samples,
                  const float* __restrict__ w1, const float* __restrict__ b1,
                  const float* __restrict__ w2, const float* __restrict__ b2,
                  const float* __restrict__ w3, const float* __restrict__ b3,
                  const float* __restrict__ w_out, const float* __restrict__ b_out,
                  float* __restrict__ out, int B)
{
    const int lane  = threadIdx.x & 63;
    const int w     = threadIdx.x >> 6;
    const int col32 = lane & 31;              // this lane's sample row (mod 32)
    const int half  = lane >> 5;              // 0..1

    const int rowBase = (blockIdx.x * 4 + w) * 32;
    const int row = rowBase + col32;

    // pi permutation: swap hidden-unit 4-blocks 1<->2 and 5<->6
    auto pi = [](int m) -> int {
        int bb = (m >> 2) & 3;
        return m + ((bb == 1) ? 4 : (bb == 2) ? -4 : 0);
    };

    // ---- scalars needed for A1 variants ----
    const float maxT = samples[7];
    const float dt   = maxT / 64.0f;
    const float dt2  = 0.5f * dt;
    const float dt6  = dt / 6.0f;

    // ---- persistent MFMA operands ----
    // Layer1 A variants: slots k=0..2 = W1 rows, k=3 = b1 (vs B's 1.0),
    // slots k=4..6 = ci*W1 rows (vs B's kprev), k=7 = 0.
    union { half2_ h2[4]; half8_ h8; } A1h, A1f;   // ci = dt2 / dt
    {
        int pm = pi(col32);
        if (half == 0) {
            float w0 = w1[0 * 32 + pm], w1v = w1[1 * 32 + pm], w2v = w1[2 * 32 + pm];
            A1h.h2[0] = (half2_){(__fp16)w0, (__fp16)w1v};
            A1h.h2[1] = (half2_){(__fp16)w2v, (__fp16)b1[pm]};
            A1h.h2[2] = (half2_){(__fp16)(dt2 * w0), (__fp16)(dt2 * w1v)};
            A1h.h2[3] = (half2_){(__fp16)(dt2 * w2v), (__fp16)0.0f};
            A1f.h2[0] = A1h.h2[0];
            A1f.h2[1] = A1h.h2[1];
            A1f.h2[2] = (half2_){(__fp16)(dt * w0), (__fp16)(dt * w1v)};
            A1f.h2[3] = (half2_){(__fp16)(dt * w2v), (__fp16)0.0f};
        } else {
#pragma unroll
            for (int pp = 0; pp < 4; ++pp) {
                A1h.h2[pp] = (half2_)(__fp16)0.0f;
                A1f.h2[pp] = (half2_)(__fp16)0.0f;
            }
        }
    }

    // W2^T A-frags: A2[m=j2][k=i1] = w2[i1*32 + j2]
    union { half2_ h2[4]; half8_ h8; } W2T1, W2T2;
#pragma unroll
    for (int pp = 0; pp < 4; ++pp) {
        int i1 = half * 8 + 2 * pp;
        W2T1.h2[pp] = (half2_){(__fp16)w2[i1 * 32 + col32], (__fp16)w2[(i1 + 1) * 32 + col32]};
        W2T2.h2[pp] = (half2_){(__fp16)w2[(i1 + 16) * 32 + col32], (__fp16)w2[(i1 + 17) * 32 + col32]};
    }
    // layer2 bias C-frag: Cb[r] = b2[j2(r)]
    float16_ Cb;
#pragma unroll
    for (int r = 0; r < 16; ++r)
        Cb[r] = b2[(r & 3) + 8 * (r >> 2) + 4 * half];

    // Layer3 A-frags with ROW DUPLICATION: rows {0,1,2} AND {4,5,6} hold
    // w3 column (m&3); D3 regs 0..2 then hold k in BOTH lane-halves.
    union { half2_ h2[4]; half8_ h8; } A31, A32;
    {
        const bool live = (col32 < 8) && ((col32 & 3) < 3);
        const int  d    = col32 & 3;
#pragma unroll
        for (int pp = 0; pp < 4; ++pp) {
            int j0 = 2 * pp;
            int nu0 = 4 * half + (j0 & 3) + 8 * (j0 >> 2);
            if (live) {
                A31.h2[pp] = (half2_){(__fp16)w3[nu0 * 3 + d], (__fp16)w3[(nu0 + 1) * 3 + d]};
                A32.h2[pp] = (half2_){(__fp16)w3[(nu0 + 16) * 3 + d], (__fp16)w3[(nu0 + 17) * 3 + d]};
            } else {
                A31.h2[pp] = (half2_)(__fp16)0.0f;
                A32.h2[pp] = (half2_)(__fp16)0.0f;
            }
        }
    }

    // shared zero C-frag (layer1 + layer3-inner)
    float16_ Zc;
#pragma unroll
    for (int r = 0; r < 16; ++r) Zc[r] = 0.0f;

    int sidx[8];
    unsigned long long smask = 0ull;
#pragma unroll
    for (int j = 0; j < 8; ++j) {
        int id = (int)rintf(samples[j] / dt) - 1;   // jnp.round = RNE
        id = id < 0 ? 0 : (id > NSTEPS - 1 ? NSTEPS - 1 : id);
        id = __builtin_amdgcn_readfirstlane(id);    // wave-uniform -> SGPR
        sidx[j] = id;
        smask |= 1ull << id;
    }
    const float wo0 = w_out[0], wo1 = w_out[1], wo2 = w_out[2];
    const float bo  = b_out[0];
    const float b30 = b3[0], b31 = b3[1], b32 = b3[2];

    float y0 = x[(size_t)row * 3 + 0];
    float y1 = x[(size_t)row * 3 + 1];
    float y2 = x[(size_t)row * 3 + 2];

    const half2_ zh = (half2_)(__fp16)0.0f;

#pragma unroll 1
    for (int s = 0; s < NSTEPS; ++s) {
        float acc0 = 0.f, acc1 = 0.f, acc2 = 0.f;

        // y-half2s once per STEP (layer1 input y-part is stage-invariant)
        half2_ yp01 = __builtin_amdgcn_cvt_pkrtz(y0, y1);
        half2_ yp2o = __builtin_amdgcn_cvt_pkrtz(y2, 1.0f);

        float k0 = 0.f, k1 = 0.f, k2 = 0.f;   // kprev (zero at st=0)

#pragma unroll
        for (int st = 0; st < 4; ++st) {
            // ---- layer1: B = (y | 1 | kprev | 0); A picks ci variant ----
            half2_ kp01 = (st == 0) ? zh : __builtin_amdgcn_cvt_pkrtz(k0, k1);
            half2_ kp2o = (st == 0) ? zh : __builtin_amdgcn_cvt_pkrtz(k2, 0.0f);
            union { half2_ h2[4]; half8_ h8; } BL1;
            BL1.h2[0] = yp01; BL1.h2[1] = yp2o;
            BL1.h2[2] = kp01; BL1.h2[3] = kp2o;

            float16_ D1 = (st == 3)
                ? __builtin_amdgcn_mfma_f32_32x32x16_f16(A1f.h8, BL1.h8, Zc, 0, 0, 0)
                : __builtin_amdgcn_mfma_f32_32x32x16_f16(A1h.h8, BL1.h8, Zc, 0, 0, 0);

            // ---- relu-pack -> layer2 B-frags (pi makes register order exact)
            union { half2_ h2[4]; half8_ h8; } B1, B2;
#pragma unroll
            for (int pp = 0; pp < 4; ++pp) {
                B1.h2[pp] = relu_pk_f16(D1[2 * pp], D1[2 * pp + 1]);
                B2.h2[pp] = relu_pk_f16(D1[8 + 2 * pp], D1[8 + 2 * pp + 1]);
            }

            // ---- layer2: chained MFMA pair (Cb inner) ----
            float16_ D2 = __builtin_amdgcn_mfma_f32_32x32x16_f16(W2T1.h8, B1.h8,
                          __builtin_amdgcn_mfma_f32_32x32x16_f16(W2T2.h8, B2.h8, Cb, 0, 0, 0), 0, 0, 0);

            // ---- relu-pack -> layer3 B-frags ----
            union { half2_ h2[4]; half8_ h8; } H1, H2;
#pragma unroll
            for (int pp = 0; pp < 4; ++pp) {
                H1.h2[pp] = relu_pk_f16(D2[2 * pp], D2[2 * pp + 1]);
                H2.h2[pp] = relu_pk_f16(D2[8 + 2 * pp], D2[8 + 2 * pp + 1]);
            }

            // ---- layer3: chained MFMA pair; dup rows -> k in every lane ----
            float16_ D3 = __builtin_amdgcn_mfma_f32_32x32x16_f16(A32.h8, H2.h8,
                          __builtin_amdgcn_mfma_f32_32x32x16_f16(A31.h8, H1.h8, Zc, 0, 0, 0), 0, 0, 0);

            k0 = D3[0] + b30;
            k1 = D3[1] + b31;
            k2 = D3[2] + b32;

            const float ca = (st == 1 || st == 2) ? 2.0f : 1.0f;
            acc0 = fmaf(ca, k0, acc0); acc1 = fmaf(ca, k1, acc1); acc2 = fmaf(ca, k2, acc2);
        }
        y0 = fmaf(dt6, acc0, y0); y1 = fmaf(dt6, acc1, y1); y2 = fmaf(dt6, acc2, y2);

        // wave-uniform SALU fast path: most steps store nothing
        if ((smask >> s) & 1ull) {
            if (half == 0) {
#pragma unroll
                for (int j = 0; j < 8; ++j) {
                    if (sidx[j] == s) {
                        out[(size_t)j * B + row] = fmaf(y2, wo2, fmaf(y1, wo1, fmaf(y0, wo0, bo)));
                    }
                }
            }
        }
    }
}

extern "C" void kernel_launch(void* const* d_in, const int* in_sizes, int n_in,
                              void* d_out, int out_size, void* d_ws, size_t ws_size,
                              hipStream_t stream) {
    const float* x       = (const float*)d_in[0];
    const float* samples = (const float*)d_in[1];
    const float* w1      = (const float*)d_in[2];
    const float* b1      = (const float*)d_in[3];
    const float* w2      = (const float*)d_in[4];
    const float* b2      = (const float*)d_in[5];
    const float* w3      = (const float*)d_in[6];
    const float* b3      = (const float*)d_in[7];
    const float* w_out   = (const float*)d_in[8];
    const float* b_out   = (const float*)d_in[9];
    float* out = (float*)d_out;

    const int B = in_sizes[0] / 3;           // 131072
    const int rowsPerBlock = 128;            // 4 waves x 32 rows (1 chain each)
    const int grid = (B + rowsPerBlock - 1) / rowsPerBlock;
    ode_rk4_mfma<<<grid, 256, 0, stream>>>(
        x, samples, w1, b1, w2, b2, w3, b3, w_out, b_out, out, B);
}